// Round 17
// baseline (140.515 us; speedup 1.0000x reference)
//
#include <hip/hip_runtime.h>

#define N_NODES 100000
#define N_EDGES 1600000
#define D_IN    128
#define D_H     8
#define N_MASK  10000

#define TS      256       // enc tile size (nodes per tile); loc fits in 8 bits
#define NTE     391       // ceil(N_NODES/TS)
#define CAPB    5760      // enc bucket capacity
#define TSD     64        // dec tile size (slots per tile); loc fits in 6 bits
#define NTD     157       // ceil(N_MASK/TSD)
#define CAPD    1536      // dec bucket capacity
#define NB_NODE 196       // node blocks in k_pre (512 nodes/block, thread-per-node)
#define EPB     2048      // edges per bucket block
#define NB_BKT  782       // ceil(N_EDGES/EPB)

__device__ __forceinline__ float lrelu(float v, float s){ return v > 0.f ? v : s*v; }

__device__ __forceinline__ float wave_sum(float v){
#pragma unroll
  for (int o = 32; o > 0; o >>= 1) v += __shfl_xor(v, o, 64);
  return v;
}

// init: mask_slot=-1, cursors=0, cos/ticket=0
__global__ void k_init(int* __restrict__ mask_slot, int* __restrict__ gcur_enc,
                       int* __restrict__ gcur_dec, float* __restrict__ cos_sum,
                       int* __restrict__ ticket){
  int i = blockIdx.x*blockDim.x + threadIdx.x;
  if (i < N_NODES) mask_slot[i] = -1;
  if (i < NTE) gcur_enc[i] = 0;
  if (i < NTD) gcur_dec[i] = 0;
  if (i == 0){ cos_sum[0] = 0.f; ticket[0] = 0; }
}

// mask_slot scatter + vvec (= dec_W^T dec_a_src) in block 0
__global__ void k_ms(const int* __restrict__ mask_nodes, int* __restrict__ mask_slot,
                     const float* __restrict__ Wd, const float* __restrict__ a_src,
                     float* __restrict__ vvec){
  int i = blockIdx.x*blockDim.x + threadIdx.x;
  if (i < N_MASK) mask_slot[mask_nodes[i]] = i;
  if (blockIdx.x == 0 && threadIdx.x < D_H){
    float s = 0.f;
    for (int j = 0; j < D_IN; ++j) s += a_src[j] * Wd[j*D_H + threadIdx.x];
    vvec[threadIdx.x] = s;
  }
}

// fused: blocks [0,NB_NODE)              = encoder node stage, thread-per-node,
//                                          explicit 8-load groups for MLP
//        blocks [NB_NODE,NB_NODE+NB_BKT) = edge bucketing (2048/block, reg-cached 2-pass)
__global__ void __launch_bounds__(512, 8) k_pre(
    const float* __restrict__ x, const float* __restrict__ token,
    const float* __restrict__ W, const float* __restrict__ a_src,
    const float* __restrict__ a_dst, const int* __restrict__ mask_slot,
    const int* __restrict__ ei,
    float* __restrict__ h1, float* __restrict__ as1, float* __restrict__ ad1,
    int* __restrict__ gcur_enc, int* __restrict__ gcur_dec,
    unsigned* __restrict__ be, unsigned* __restrict__ bd){
  __shared__ int smem[1104];   // node: Ws(1024)+sa+sd ; bucket: hist/base arrays
  if (blockIdx.x < NB_NODE){
    float* Ws = (float*)smem;
    float* sa = Ws + D_H*D_IN;
    float* sd = sa + D_H;
    int tid = threadIdx.x;
    int wid = blockIdx.x*512 + tid;
    int msl = (wid < N_NODES) ? mask_slot[wid] : 0;   // issue early, overlap with Ws stage
    for (int t = tid; t < D_H*D_IN; t += 512) Ws[t] = W[t];
    if (tid < D_H)            sa[tid] = a_src[tid];
    else if (tid < 2*D_H)     sd[tid - D_H] = a_dst[tid - D_H];
    __syncthreads();
    if (wid >= N_NODES) return;
    const float* row = (msl >= 0) ? token : (x + (size_t)wid*D_IN);
    float acc[D_H];
#pragma unroll
    for (int j = 0; j < D_H; ++j) acc[j] = 0.f;
    for (int g = 0; g < 4; ++g){           // 4 groups x 128B: 8 loads in flight per group
      float4 xv[8];
#pragma unroll
      for (int l = 0; l < 8; ++l) xv[l] = *(const float4*)(row + g*32 + 4*l);
#pragma unroll
      for (int l = 0; l < 8; ++l){
#pragma unroll
        for (int j = 0; j < D_H; ++j){
          float4 wv = *(const float4*)(Ws + j*D_IN + g*32 + 4*l);   // uniform -> broadcast
          acc[j] += xv[l].x*wv.x + xv[l].y*wv.y + xv[l].z*wv.z + xv[l].w*wv.w;
        }
      }
    }
    float as = 0.f, ad = 0.f;
#pragma unroll
    for (int j = 0; j < D_H; ++j){ as += acc[j]*sa[j]; ad += acc[j]*sd[j]; }
    float4* hp = (float4*)(h1 + (size_t)wid*D_H);
    hp[0] = make_float4(acc[0], acc[1], acc[2], acc[3]);
    hp[1] = make_float4(acc[4], acc[5], acc[6], acc[7]);
    as1[wid] = as; ad1[wid] = ad;
  } else {
    int* h_enc    = smem;                  // [NTE]
    int* base_enc = h_enc + NTE;           // [NTE]
    int* h_dec    = base_enc + NTE;        // [NTD]
    int* base_dec = h_dec + NTD;           // [NTD]
    int tid = threadIdx.x;
    if (tid < NTE) h_enc[tid] = 0;
    if (tid < NTD) h_dec[tid] = 0;
    __syncthreads();
    int t0 = (blockIdx.x - NB_NODE)*EPB;
    int s[4], d[4], sl[4];
#pragma unroll
    for (int k = 0; k < 4; ++k){
      int t = t0 + tid + k*512;
      s[k] = -1;
      if (t < N_EDGES){
        s[k] = ei[t]; d[k] = ei[N_EDGES + t];
        sl[k] = mask_slot[d[k]];
        atomicAdd(&h_enc[d[k] >> 8], 1);
        if (sl[k] >= 0) atomicAdd(&h_dec[sl[k] >> 6], 1);
      }
    }
    __syncthreads();
    if (tid < NTE){ base_enc[tid] = atomicAdd(&gcur_enc[tid], h_enc[tid]); h_enc[tid] = 0; }
    if (tid < NTD){ base_dec[tid] = atomicAdd(&gcur_dec[tid], h_dec[tid]); h_dec[tid] = 0; }
    __syncthreads();
#pragma unroll
    for (int k = 0; k < 4; ++k){
      if (s[k] >= 0){
        int b = d[k] >> 8, loc = d[k] & 255;
        int idx = base_enc[b] + atomicAdd(&h_enc[b], 1);
        if (idx < CAPB) be[(size_t)b*CAPB + idx] = ((unsigned)s[k] << 8) | (unsigned)loc;
        if (sl[k] >= 0){
          int bs = sl[k] >> 6, locs = sl[k] & 63;
          int i2 = base_dec[bs] + atomicAdd(&h_dec[bs], 1);
          if (i2 < CAPD) bd[(size_t)bs*CAPD + i2] = ((unsigned)s[k] << 6) | (unsigned)locs;
        }
      }
    }
  }
}

// one block per enc tile: counting-sort bucket by loc in LDS, then 2 threads/node
// register accumulation (unroll-4), combine, analytic self-loop, fused enc_fin epilogue.
__global__ void __launch_bounds__(512) k_agg_enc(const unsigned* __restrict__ be,
                          const int* __restrict__ gcur_enc,
                          const float* __restrict__ as1, const float* __restrict__ ad1,
                          const float* __restrict__ h1,
                          const float* __restrict__ enc_b, const float* __restrict__ e2dW,
                          const int* __restrict__ mask_slot, const float* __restrict__ v,
                          float* __restrict__ out_rep, float* __restrict__ rep,
                          float* __restrict__ ex2){
  __shared__ unsigned sorted[CAPB];
  __shared__ int hist[TS], off[TS], cur[TS];
  __shared__ float lad[TS];
  __shared__ float comb[TS*9];
  int tau = blockIdx.x, tid = threadIdx.x;
  int gb = tau*TS;
  if (tid < TS){
    hist[tid] = 0;
    int g = gb + tid; lad[tid] = (g < N_NODES) ? ad1[g] : 0.f;
  }
  __syncthreads();
  int n = min(gcur_enc[tau], CAPB);
  const unsigned* bb = be + (size_t)tau*CAPB;
  for (int i = tid; i < n; i += 512) atomicAdd(&hist[bb[i] & 255], 1);
  __syncthreads();
  if (tid < TS) off[tid] = hist[tid];
  __syncthreads();
#pragma unroll
  for (int s2 = 1; s2 < TS; s2 <<= 1){          // inclusive prefix sum (Hillis-Steele)
    int vv = 0;
    if (tid < TS && tid >= s2) vv = off[tid - s2];
    __syncthreads();
    if (tid < TS) off[tid] += vv;
    __syncthreads();
  }
  if (tid < TS) cur[tid] = off[tid] - hist[tid];   // exclusive start
  __syncthreads();
  for (int i = tid; i < n; i += 512){
    unsigned w = bb[i];
    int pos = atomicAdd(&cur[w & 255], 1);
    sorted[pos] = w;
  }
  __syncthreads();
  // phase 2: 2 threads per node, register accumulation over sorted run halves
  int c = tid & 255, half = tid >> 8;
  int start = off[c] - hist[c], deg = hist[c];
  int mid = start + ((deg + 1) >> 1), end = start + deg;
  int k0 = half ? mid : start, k1 = half ? end : mid;
  float adv = lad[c];
  float acc[9];
#pragma unroll
  for (int j = 0; j < 9; ++j) acc[j] = 0.f;
  auto edge1 = [&](unsigned w){
    int s = w >> 8;
    float as = as1[s];
    float4 ha = *(const float4*)(h1 + (size_t)s*D_H);
    float4 hb = *(const float4*)(h1 + (size_t)s*D_H + 4);
    float ex = __expf(lrelu(as + adv, 0.2f));
    acc[0] += ex*ha.x; acc[1] += ex*ha.y; acc[2] += ex*ha.z; acc[3] += ex*ha.w;
    acc[4] += ex*hb.x; acc[5] += ex*hb.y; acc[6] += ex*hb.z; acc[7] += ex*hb.w;
    acc[8] += ex;
  };
  int k = k0;
  for (; k + 4 <= k1; k += 4){
    unsigned w0 = sorted[k], w1 = sorted[k+1], w2 = sorted[k+2], w3 = sorted[k+3];
    int s0 = w0 >> 8, s1 = w1 >> 8, s2 = w2 >> 8, s3 = w3 >> 8;
    float a0 = as1[s0], a1 = as1[s1], a2 = as1[s2], a3 = as1[s3];
    float4 h0a = *(const float4*)(h1 + (size_t)s0*D_H), h0b = *(const float4*)(h1 + (size_t)s0*D_H + 4);
    float4 h1a = *(const float4*)(h1 + (size_t)s1*D_H), h1b = *(const float4*)(h1 + (size_t)s1*D_H + 4);
    float4 h2a = *(const float4*)(h1 + (size_t)s2*D_H), h2b = *(const float4*)(h1 + (size_t)s2*D_H + 4);
    float4 h3a = *(const float4*)(h1 + (size_t)s3*D_H), h3b = *(const float4*)(h1 + (size_t)s3*D_H + 4);
    float e0 = __expf(lrelu(a0 + adv, 0.2f));
    float e1 = __expf(lrelu(a1 + adv, 0.2f));
    float e2 = __expf(lrelu(a2 + adv, 0.2f));
    float e3 = __expf(lrelu(a3 + adv, 0.2f));
    acc[0] += e0*h0a.x + e1*h1a.x + e2*h2a.x + e3*h3a.x;
    acc[1] += e0*h0a.y + e1*h1a.y + e2*h2a.y + e3*h3a.y;
    acc[2] += e0*h0a.z + e1*h1a.z + e2*h2a.z + e3*h3a.z;
    acc[3] += e0*h0a.w + e1*h1a.w + e2*h2a.w + e3*h3a.w;
    acc[4] += e0*h0b.x + e1*h1b.x + e2*h2b.x + e3*h3b.x;
    acc[5] += e0*h0b.y + e1*h1b.y + e2*h2b.y + e3*h3b.y;
    acc[6] += e0*h0b.z + e1*h1b.z + e2*h2b.z + e3*h3b.z;
    acc[7] += e0*h0b.w + e1*h1b.w + e2*h2b.w + e3*h3b.w;
    acc[8] += e0 + e1 + e2 + e3;
  }
  for (; k < k1; ++k) edge1(sorted[k]);
  if (half){
#pragma unroll
    for (int j = 0; j < 9; ++j) comb[c*9 + j] = acc[j];
  }
  __syncthreads();
  if (!half){
    int i = gb + c;
    if (i < N_NODES){
#pragma unroll
      for (int j = 0; j < 9; ++j) acc[j] += comb[c*9 + j];
      // analytic self-loop
      {
        float exs = __expf(lrelu(as1[i] + adv, 0.2f));
        float4 ha = *(const float4*)(h1 + (size_t)i*D_H);
        float4 hb = *(const float4*)(h1 + (size_t)i*D_H + 4);
        acc[0] += exs*ha.x; acc[1] += exs*ha.y; acc[2] += exs*ha.z; acc[3] += exs*ha.w;
        acc[4] += exs*hb.x; acc[5] += exs*hb.y; acc[6] += exs*hb.z; acc[7] += exs*hb.w;
        acc[8] += exs;
      }
      float inv = 1.0f / acc[8];
      float er[D_H];
#pragma unroll
      for (int j = 0; j < D_H; ++j){
        er[j] = lrelu(acc[j]*inv + enc_b[j], 0.01f);
        out_rep[(size_t)i*D_H + j] = er[j];
      }
      bool masked = mask_slot[i] >= 0;
      float as = 0.f;
      float rv[D_H];
#pragma unroll
      for (int kk = 0; kk < D_H; ++kk){
        float t = 0.f;
#pragma unroll
        for (int j = 0; j < D_H; ++j) t += er[j]*e2dW[kk*D_H + j];
        t = masked ? 0.f : t;
        rv[kk] = t;
        as += t * v[kk];
      }
      float4* rp = (float4*)(rep + (size_t)i*D_H);
      rp[0] = make_float4(rv[0], rv[1], rv[2], rv[3]);
      rp[1] = make_float4(rv[4], rv[5], rv[6], rv[7]);
      ex2[i] = __expf(lrelu(as, 0.2f));  // alpha_dst[masked]=0 -> weight depends only on src
    }
  }
}

// one block per dec tile (157): sort 64-bin, 8 threads/slot register-accumulate,
// shfl-combine, analytic self-loop (+1 denom), fused cosine loss.
__global__ void __launch_bounds__(512) k_agg_dec(const unsigned* __restrict__ bd,
                          const int* __restrict__ gcur_dec,
                          const float* __restrict__ ex2, const float* __restrict__ rep,
                          const float* __restrict__ Wd, const float* __restrict__ dec_b,
                          const int* __restrict__ mask_nodes, const float* __restrict__ x,
                          float* __restrict__ cos_sum, int* __restrict__ ticket,
                          float* __restrict__ out){
  __shared__ unsigned sorted[CAPD];
  __shared__ int hist[TSD], off[TSD], cur[TSD];
  __shared__ float comb[TSD*9];
  __shared__ float Wt[D_H*D_IN];    // transposed: Wt[k*128+f] = Wd[f*8+k]
  __shared__ float wsum[8];
  int sg = blockIdx.x, tid = threadIdx.x;
  if (tid < TSD) hist[tid] = 0;
  for (int t = tid; t < D_H*D_IN; t += 512) Wt[(t & 7)*D_IN + (t >> 3)] = Wd[t];
  __syncthreads();
  int n = min(gcur_dec[sg], CAPD);
  const unsigned* bb = bd + (size_t)sg*CAPD;
  for (int i = tid; i < n; i += 512) atomicAdd(&hist[bb[i] & 63], 1);
  __syncthreads();
  if (tid < TSD) off[tid] = hist[tid];
  __syncthreads();
#pragma unroll
  for (int s2 = 1; s2 < TSD; s2 <<= 1){
    int vv = 0;
    if (tid < TSD && tid >= s2) vv = off[tid - s2];
    __syncthreads();
    if (tid < TSD) off[tid] += vv;
    __syncthreads();
  }
  if (tid < TSD) cur[tid] = off[tid] - hist[tid];
  __syncthreads();
  for (int i = tid; i < n; i += 512){
    unsigned w = bb[i];
    int pos = atomicAdd(&cur[w & 63], 1);
    sorted[pos] = w;
  }
  __syncthreads();
  // 8 threads per slot: strided walk, unroll-2
  int c = tid >> 3, part = tid & 7;
  int start = off[c] - hist[c], deg = hist[c], end = start + deg;
  float acc[9];
#pragma unroll
  for (int j = 0; j < 9; ++j) acc[j] = 0.f;
  int k = start + part;
  for (; k + 8 < end; k += 16){
    unsigned w0 = sorted[k], w1 = sorted[k+8];
    int sA = w0 >> 6, sB = w1 >> 6;
    float eA = ex2[sA], eB = ex2[sB];
    float4 raA = *(const float4*)(rep + (size_t)sA*D_H);
    float4 rbA = *(const float4*)(rep + (size_t)sA*D_H + 4);
    float4 raB = *(const float4*)(rep + (size_t)sB*D_H);
    float4 rbB = *(const float4*)(rep + (size_t)sB*D_H + 4);
    acc[0] += eA*raA.x; acc[1] += eA*raA.y; acc[2] += eA*raA.z; acc[3] += eA*raA.w;
    acc[4] += eA*rbA.x; acc[5] += eA*rbA.y; acc[6] += eA*rbA.z; acc[7] += eA*rbA.w;
    acc[8] += eA;
    acc[0] += eB*raB.x; acc[1] += eB*raB.y; acc[2] += eB*raB.z; acc[3] += eB*raB.w;
    acc[4] += eB*rbB.x; acc[5] += eB*rbB.y; acc[6] += eB*rbB.z; acc[7] += eB*rbB.w;
    acc[8] += eB;
  }
  if (k < end){
    unsigned w = sorted[k];
    int s = w >> 6;
    float E = ex2[s];
    float4 ra = *(const float4*)(rep + (size_t)s*D_H);
    float4 rb = *(const float4*)(rep + (size_t)s*D_H + 4);
    acc[0] += E*ra.x; acc[1] += E*ra.y; acc[2] += E*ra.z; acc[3] += E*ra.w;
    acc[4] += E*rb.x; acc[5] += E*rb.y; acc[6] += E*rb.z; acc[7] += E*rb.w;
    acc[8] += E;
  }
  // combine across the 8 lanes of the slot group
#pragma unroll
  for (int j = 0; j < 9; ++j){
    acc[j] += __shfl_xor(acc[j], 1, 64);
    acc[j] += __shfl_xor(acc[j], 2, 64);
    acc[j] += __shfl_xor(acc[j], 4, 64);
  }
  if (part == 0){
    acc[8] += 1.0f;   // analytic self-loop: rep[masked]=0 -> ex2=1, denom-only
#pragma unroll
    for (int j = 0; j < 9; ++j) comb[c*9 + j] = acc[j];
  }
  __syncthreads();
  // fused loss: 8 waves sweep the tile's slots (wave-uniform comb reads -> broadcast)
  int wv = tid >> 6, lane = tid & 63;
  float accv = 0.f;
  for (int sl = wv; sl < TSD; sl += 8){
    int slot = sg*TSD + sl;
    if (slot >= N_MASK) break;
    const float* a = comb + sl*9;
    float inv = 1.0f / a[8];
    int node = mask_nodes[slot];
    float dot = 0.f, na = 0.f, nb = 0.f;
#pragma unroll
    for (int hh = 0; hh < 2; ++hh){
      int f = lane + 64*hh;
      float r = dec_b[f];
#pragma unroll
      for (int kk = 0; kk < D_H; ++kk) r += a[kk]*inv*Wt[kk*D_IN + f];
      r = lrelu(r, 0.01f);
      float xi = x[(size_t)node*D_IN + f];
      dot += r*xi; na += r*r; nb += xi*xi;
    }
    dot = wave_sum(dot); na = wave_sum(na); nb = wave_sum(nb);
    if (lane == 0) accv += dot / (fmaxf(sqrtf(na), 1e-8f)*fmaxf(sqrtf(nb), 1e-8f));
  }
  if (lane == 0) wsum[wv] = accv;
  __syncthreads();
  if (tid == 0){
    float b = 0.f;
#pragma unroll
    for (int q = 0; q < 8; ++q) b += wsum[q];
    atomicAdd(cos_sum, b);
    __threadfence();
    int t = atomicAdd(ticket, 1);
    if (t == gridDim.x - 1){
      float cc = atomicAdd(cos_sum, 0.0f);   // atomic read-after-all
      out[0] = 1.0f - cc / (float)N_MASK;
    }
  }
}

extern "C" void kernel_launch(void* const* d_in, const int* in_sizes, int n_in,
                              void* d_out, int out_size, void* d_ws, size_t ws_size,
                              hipStream_t stream){
  const float* x          = (const float*)d_in[0];
  const int*   ei         = (const int*)  d_in[1];
  const int*   mask_nodes = (const int*)  d_in[2];
  const float* token      = (const float*)d_in[3];
  const float* enc_W      = (const float*)d_in[4];
  const float* enc_as     = (const float*)d_in[5];
  const float* enc_ad     = (const float*)d_in[6];
  const float* enc_b      = (const float*)d_in[7];
  const float* e2d_W      = (const float*)d_in[8];
  const float* dec_W      = (const float*)d_in[9];
  const float* dec_as     = (const float*)d_in[10];
  const float* dec_b      = (const float*)d_in[12];
  float* out = (float*)d_out;

  char* w = (char*)d_ws;
  size_t off = 0;
  auto alloc = [&](size_t bytes)->char*{ char* p = w + off; off += (bytes + 255)/256*256; return p; };
  int*   gcur_enc = (int*)  alloc(NTE*4);
  int*   gcur_dec = (int*)  alloc(NTD*4);
  float* cos_sum  = (float*)alloc(4);
  int*   ticket   = (int*)  alloc(4);
  int*      mask_slot = (int*)     alloc((size_t)N_NODES*4);
  unsigned* be        = (unsigned*)alloc((size_t)NTE*CAPB*4);
  unsigned* bd        = (unsigned*)alloc((size_t)NTD*CAPD*4);
  float*    h1        = (float*)   alloc((size_t)N_NODES*D_H*4);
  float*    as1       = (float*)   alloc((size_t)N_NODES*4);
  float*    ad1       = (float*)   alloc((size_t)N_NODES*4);
  float*    rep       = (float*)   alloc((size_t)N_NODES*D_H*4);
  float*    ex2       = (float*)   alloc((size_t)N_NODES*4);
  float*    vvec      = (float*)   alloc(64);

  k_init    <<<(N_NODES + 511)/512, 512, 0, stream>>>(mask_slot, gcur_enc, gcur_dec, cos_sum, ticket);
  k_ms      <<<(N_MASK + 255)/256, 256, 0, stream>>>(mask_nodes, mask_slot, dec_W, dec_as, vvec);
  k_pre     <<<NB_NODE + NB_BKT, 512, 0, stream>>>(x, token, enc_W, enc_as, enc_ad, mask_slot,
                                                   ei, h1, as1, ad1, gcur_enc, gcur_dec, be, bd);
  k_agg_enc <<<NTE, 512, 0, stream>>>(be, gcur_enc, as1, ad1, h1, enc_b, e2d_W, mask_slot,
                                      vvec, out + 1, rep, ex2);
  k_agg_dec <<<NTD, 512, 0, stream>>>(bd, gcur_dec, ex2, rep, dec_W, dec_b, mask_nodes, x,
                                      cos_sum, ticket, out);
}

// Round 19
// 92.508 us; speedup vs baseline: 1.5190x; 1.5190x over previous
//
#include <hip/hip_runtime.h>

#define N_NODES 100000
#define N_EDGES 1600000
#define D_IN    128
#define D_H     8
#define N_MASK  10000

#define TS      256       // enc tile size (nodes per tile); loc fits in 8 bits
#define NTE     391       // ceil(N_NODES/TS)
#define CAPB    5760      // enc bucket capacity
#define TSD     64        // dec tile size (slots per tile); loc fits in 6 bits
#define NTD     157       // ceil(N_MASK/TSD)
#define CAPD    1536      // dec bucket capacity
#define NB_NODE 391       // node blocks in k_pre (256 nodes/block, 2 threads/node)
#define EPB     2048      // edges per bucket block
#define NB_BKT  782       // ceil(N_EDGES/EPB)

__device__ __forceinline__ float lrelu(float v, float s){ return v > 0.f ? v : s*v; }

__device__ __forceinline__ float wave_sum(float v){
#pragma unroll
  for (int o = 32; o > 0; o >>= 1) v += __shfl_xor(v, o, 64);
  return v;
}

// init: mask_slot=-1, cursors=0, cos/ticket=0
__global__ void k_init(int* __restrict__ mask_slot, int* __restrict__ gcur_enc,
                       int* __restrict__ gcur_dec, float* __restrict__ cos_sum,
                       int* __restrict__ ticket){
  int i = blockIdx.x*blockDim.x + threadIdx.x;
  if (i < N_NODES) mask_slot[i] = -1;
  if (i < NTE) gcur_enc[i] = 0;
  if (i < NTD) gcur_dec[i] = 0;
  if (i == 0){ cos_sum[0] = 0.f; ticket[0] = 0; }
}

// mask_slot scatter + vvec (= dec_W^T dec_a_src) in block 0
__global__ void k_ms(const int* __restrict__ mask_nodes, int* __restrict__ mask_slot,
                     const float* __restrict__ Wd, const float* __restrict__ a_src,
                     float* __restrict__ vvec){
  int i = blockIdx.x*blockDim.x + threadIdx.x;
  if (i < N_MASK) mask_slot[mask_nodes[i]] = i;
  if (blockIdx.x == 0 && threadIdx.x < D_H){
    float s = 0.f;
    for (int j = 0; j < D_IN; ++j) s += a_src[j] * Wd[j*D_H + threadIdx.x];
    vvec[threadIdx.x] = s;
  }
}

// fused: blocks [0,NB_NODE)              = encoder node stage, 2 threads/node
//        blocks [NB_NODE,NB_NODE+NB_BKT) = edge bucketing (2048/block, reg-cached 2-pass)
__global__ void __launch_bounds__(512) k_pre(
    const float* __restrict__ x, const float* __restrict__ token,
    const float* __restrict__ W, const float* __restrict__ a_src,
    const float* __restrict__ a_dst, const int* __restrict__ mask_slot,
    const int* __restrict__ ei,
    float* __restrict__ h1, float* __restrict__ as1, float* __restrict__ ad1,
    int* __restrict__ gcur_enc, int* __restrict__ gcur_dec,
    unsigned* __restrict__ be, unsigned* __restrict__ bd){
  __shared__ int smem[1104];   // node: Ws(1024)+sa+sd ; bucket: hist/base arrays
  if (blockIdx.x < NB_NODE){
    float* Ws = (float*)smem;
    float* sa = Ws + D_H*D_IN;
    float* sd = sa + D_H;
    int tid = threadIdx.x;
    int node = blockIdx.x*256 + (tid >> 1);
    int half = tid & 1;
    int msl = (node < N_NODES) ? mask_slot[node] : 0;   // issue early
    for (int t = tid; t < D_H*D_IN; t += 512) Ws[t] = W[t];
    if (tid < D_H)            sa[tid] = a_src[tid];
    else if (tid < 2*D_H)     sd[tid - D_H] = a_dst[tid - D_H];
    __syncthreads();
    if (node >= N_NODES) return;
    const float* row = (msl >= 0) ? token : (x + (size_t)node*D_IN);
    const float* base = row + half*64;          // this lane's 64 columns (16 float4 loads)
    float acc[D_H];
#pragma unroll
    for (int j = 0; j < D_H; ++j) acc[j] = 0.f;
#pragma unroll 8
    for (int i2 = 0; i2 < 16; ++i2){
      float4 xc = *(const float4*)(base + 4*i2);
#pragma unroll
      for (int j = 0; j < D_H; ++j){
        float4 wv = *(const float4*)(Ws + j*D_IN + half*64 + 4*i2);   // 2 addrs/wave: free
        acc[j] += xc.x*wv.x + xc.y*wv.y + xc.z*wv.z + xc.w*wv.w;
      }
    }
    // combine the two halves (adjacent lanes)
#pragma unroll
    for (int j = 0; j < D_H; ++j) acc[j] += __shfl_xor(acc[j], 1, 64);
    if (half == 0){
      float as = 0.f, ad = 0.f;
#pragma unroll
      for (int j = 0; j < D_H; ++j){ as += acc[j]*sa[j]; ad += acc[j]*sd[j]; }
      float4* hp = (float4*)(h1 + (size_t)node*D_H);
      hp[0] = make_float4(acc[0], acc[1], acc[2], acc[3]);
      hp[1] = make_float4(acc[4], acc[5], acc[6], acc[7]);
      as1[node] = as; ad1[node] = ad;
    }
  } else {
    int* h_enc    = smem;                  // [NTE]
    int* base_enc = h_enc + NTE;           // [NTE]
    int* h_dec    = base_enc + NTE;        // [NTD]
    int* base_dec = h_dec + NTD;           // [NTD]
    int tid = threadIdx.x;
    if (tid < NTE) h_enc[tid] = 0;
    if (tid < NTD) h_dec[tid] = 0;
    __syncthreads();
    int t0 = (blockIdx.x - NB_NODE)*EPB;
    int s[4], d[4], sl[4];
#pragma unroll
    for (int k = 0; k < 4; ++k){
      int t = t0 + tid + k*512;
      s[k] = -1;
      if (t < N_EDGES){
        s[k] = ei[t]; d[k] = ei[N_EDGES + t];
        sl[k] = mask_slot[d[k]];
        atomicAdd(&h_enc[d[k] >> 8], 1);
        if (sl[k] >= 0) atomicAdd(&h_dec[sl[k] >> 6], 1);
      }
    }
    __syncthreads();
    if (tid < NTE){ base_enc[tid] = atomicAdd(&gcur_enc[tid], h_enc[tid]); h_enc[tid] = 0; }
    if (tid < NTD){ base_dec[tid] = atomicAdd(&gcur_dec[tid], h_dec[tid]); h_dec[tid] = 0; }
    __syncthreads();
#pragma unroll
    for (int k = 0; k < 4; ++k){
      if (s[k] >= 0){
        int b = d[k] >> 8, loc = d[k] & 255;
        int idx = base_enc[b] + atomicAdd(&h_enc[b], 1);
        if (idx < CAPB) be[(size_t)b*CAPB + idx] = ((unsigned)s[k] << 8) | (unsigned)loc;
        if (sl[k] >= 0){
          int bs = sl[k] >> 6, locs = sl[k] & 63;
          int i2 = base_dec[bs] + atomicAdd(&h_dec[bs], 1);
          if (i2 < CAPD) bd[(size_t)bs*CAPD + i2] = ((unsigned)s[k] << 6) | (unsigned)locs;
        }
      }
    }
  }
}

// one block per enc tile: counting-sort bucket by loc in LDS, then 2 threads/node
// register accumulation (unroll-4), combine, analytic self-loop, fused enc_fin epilogue.
__global__ void __launch_bounds__(512) k_agg_enc(const unsigned* __restrict__ be,
                          const int* __restrict__ gcur_enc,
                          const float* __restrict__ as1, const float* __restrict__ ad1,
                          const float* __restrict__ h1,
                          const float* __restrict__ enc_b, const float* __restrict__ e2dW,
                          const int* __restrict__ mask_slot, const float* __restrict__ v,
                          float* __restrict__ out_rep, float* __restrict__ rep,
                          float* __restrict__ ex2){
  __shared__ unsigned sorted[CAPB];
  __shared__ int hist[TS], off[TS], cur[TS];
  __shared__ float lad[TS];
  __shared__ float comb[TS*9];
  int tau = blockIdx.x, tid = threadIdx.x;
  int gb = tau*TS;
  if (tid < TS){
    hist[tid] = 0;
    int g = gb + tid; lad[tid] = (g < N_NODES) ? ad1[g] : 0.f;
  }
  __syncthreads();
  int n = min(gcur_enc[tau], CAPB);
  const unsigned* bb = be + (size_t)tau*CAPB;
  for (int i = tid; i < n; i += 512) atomicAdd(&hist[bb[i] & 255], 1);
  __syncthreads();
  if (tid < TS) off[tid] = hist[tid];
  __syncthreads();
#pragma unroll
  for (int s2 = 1; s2 < TS; s2 <<= 1){          // inclusive prefix sum (Hillis-Steele)
    int vv = 0;
    if (tid < TS && tid >= s2) vv = off[tid - s2];
    __syncthreads();
    if (tid < TS) off[tid] += vv;
    __syncthreads();
  }
  if (tid < TS) cur[tid] = off[tid] - hist[tid];   // exclusive start
  __syncthreads();
  for (int i = tid; i < n; i += 512){
    unsigned w = bb[i];
    int pos = atomicAdd(&cur[w & 255], 1);
    sorted[pos] = w;
  }
  __syncthreads();
  // phase 2: 2 threads per node, register accumulation over sorted run halves
  int c = tid & 255, half = tid >> 8;
  int start = off[c] - hist[c], deg = hist[c];
  int mid = start + ((deg + 1) >> 1), end = start + deg;
  int k0 = half ? mid : start, k1 = half ? end : mid;
  float adv = lad[c];
  float acc[9];
#pragma unroll
  for (int j = 0; j < 9; ++j) acc[j] = 0.f;
  auto edge1 = [&](unsigned w){
    int s = w >> 8;
    float as = as1[s];
    float4 ha = *(const float4*)(h1 + (size_t)s*D_H);
    float4 hb = *(const float4*)(h1 + (size_t)s*D_H + 4);
    float ex = __expf(lrelu(as + adv, 0.2f));
    acc[0] += ex*ha.x; acc[1] += ex*ha.y; acc[2] += ex*ha.z; acc[3] += ex*ha.w;
    acc[4] += ex*hb.x; acc[5] += ex*hb.y; acc[6] += ex*hb.z; acc[7] += ex*hb.w;
    acc[8] += ex;
  };
  int k = k0;
  for (; k + 4 <= k1; k += 4){
    unsigned w0 = sorted[k], w1 = sorted[k+1], w2 = sorted[k+2], w3 = sorted[k+3];
    int s0 = w0 >> 8, s1 = w1 >> 8, s2 = w2 >> 8, s3 = w3 >> 8;
    float a0 = as1[s0], a1 = as1[s1], a2 = as1[s2], a3 = as1[s3];
    float4 h0a = *(const float4*)(h1 + (size_t)s0*D_H), h0b = *(const float4*)(h1 + (size_t)s0*D_H + 4);
    float4 h1a = *(const float4*)(h1 + (size_t)s1*D_H), h1b = *(const float4*)(h1 + (size_t)s1*D_H + 4);
    float4 h2a = *(const float4*)(h1 + (size_t)s2*D_H), h2b = *(const float4*)(h1 + (size_t)s2*D_H + 4);
    float4 h3a = *(const float4*)(h1 + (size_t)s3*D_H), h3b = *(const float4*)(h1 + (size_t)s3*D_H + 4);
    float e0 = __expf(lrelu(a0 + adv, 0.2f));
    float e1 = __expf(lrelu(a1 + adv, 0.2f));
    float e2 = __expf(lrelu(a2 + adv, 0.2f));
    float e3 = __expf(lrelu(a3 + adv, 0.2f));
    acc[0] += e0*h0a.x + e1*h1a.x + e2*h2a.x + e3*h3a.x;
    acc[1] += e0*h0a.y + e1*h1a.y + e2*h2a.y + e3*h3a.y;
    acc[2] += e0*h0a.z + e1*h1a.z + e2*h2a.z + e3*h3a.z;
    acc[3] += e0*h0a.w + e1*h1a.w + e2*h2a.w + e3*h3a.w;
    acc[4] += e0*h0b.x + e1*h1b.x + e2*h2b.x + e3*h3b.x;
    acc[5] += e0*h0b.y + e1*h1b.y + e2*h2b.y + e3*h3b.y;
    acc[6] += e0*h0b.z + e1*h1b.z + e2*h2b.z + e3*h3b.z;
    acc[7] += e0*h0b.w + e1*h1b.w + e2*h2b.w + e3*h3b.w;
    acc[8] += e0 + e1 + e2 + e3;
  }
  for (; k < k1; ++k) edge1(sorted[k]);
  if (half){
#pragma unroll
    for (int j = 0; j < 9; ++j) comb[c*9 + j] = acc[j];
  }
  __syncthreads();
  if (!half){
    int i = gb + c;
    if (i < N_NODES){
#pragma unroll
      for (int j = 0; j < 9; ++j) acc[j] += comb[c*9 + j];
      // analytic self-loop
      {
        float exs = __expf(lrelu(as1[i] + adv, 0.2f));
        float4 ha = *(const float4*)(h1 + (size_t)i*D_H);
        float4 hb = *(const float4*)(h1 + (size_t)i*D_H + 4);
        acc[0] += exs*ha.x; acc[1] += exs*ha.y; acc[2] += exs*ha.z; acc[3] += exs*ha.w;
        acc[4] += exs*hb.x; acc[5] += exs*hb.y; acc[6] += exs*hb.z; acc[7] += exs*hb.w;
        acc[8] += exs;
      }
      float inv = 1.0f / acc[8];
      float er[D_H];
#pragma unroll
      for (int j = 0; j < D_H; ++j){
        er[j] = lrelu(acc[j]*inv + enc_b[j], 0.01f);
        out_rep[(size_t)i*D_H + j] = er[j];
      }
      bool masked = mask_slot[i] >= 0;
      float as = 0.f;
      float rv[D_H];
#pragma unroll
      for (int kk = 0; kk < D_H; ++kk){
        float t = 0.f;
#pragma unroll
        for (int j = 0; j < D_H; ++j) t += er[j]*e2dW[kk*D_H + j];
        t = masked ? 0.f : t;
        rv[kk] = t;
        as += t * v[kk];
      }
      float4* rp = (float4*)(rep + (size_t)i*D_H);
      rp[0] = make_float4(rv[0], rv[1], rv[2], rv[3]);
      rp[1] = make_float4(rv[4], rv[5], rv[6], rv[7]);
      ex2[i] = __expf(lrelu(as, 0.2f));  // alpha_dst[masked]=0 -> weight depends only on src
    }
  }
}

// one block per dec tile (157): sort 64-bin, 8 threads/slot register-accumulate,
// shfl-combine, analytic self-loop (+1 denom), fused cosine loss.
__global__ void __launch_bounds__(512) k_agg_dec(const unsigned* __restrict__ bd,
                          const int* __restrict__ gcur_dec,
                          const float* __restrict__ ex2, const float* __restrict__ rep,
                          const float* __restrict__ Wd, const float* __restrict__ dec_b,
                          const int* __restrict__ mask_nodes, const float* __restrict__ x,
                          float* __restrict__ cos_sum, int* __restrict__ ticket,
                          float* __restrict__ out){
  __shared__ unsigned sorted[CAPD];
  __shared__ int hist[TSD], off[TSD], cur[TSD];
  __shared__ float comb[TSD*9];
  __shared__ float Wt[D_H*D_IN];    // transposed: Wt[k*128+f] = Wd[f*8+k]
  __shared__ float wsum[8];
  int sg = blockIdx.x, tid = threadIdx.x;
  if (tid < TSD) hist[tid] = 0;
  for (int t = tid; t < D_H*D_IN; t += 512) Wt[(t & 7)*D_IN + (t >> 3)] = Wd[t];
  __syncthreads();
  int n = min(gcur_dec[sg], CAPD);
  const unsigned* bb = bd + (size_t)sg*CAPD;
  for (int i = tid; i < n; i += 512) atomicAdd(&hist[bb[i] & 63], 1);
  __syncthreads();
  if (tid < TSD) off[tid] = hist[tid];
  __syncthreads();
#pragma unroll
  for (int s2 = 1; s2 < TSD; s2 <<= 1){
    int vv = 0;
    if (tid < TSD && tid >= s2) vv = off[tid - s2];
    __syncthreads();
    if (tid < TSD) off[tid] += vv;
    __syncthreads();
  }
  if (tid < TSD) cur[tid] = off[tid] - hist[tid];
  __syncthreads();
  for (int i = tid; i < n; i += 512){
    unsigned w = bb[i];
    int pos = atomicAdd(&cur[w & 63], 1);
    sorted[pos] = w;
  }
  __syncthreads();
  // 8 threads per slot: strided walk, unroll-2
  int c = tid >> 3, part = tid & 7;
  int start = off[c] - hist[c], deg = hist[c], end = start + deg;
  float acc[9];
#pragma unroll
  for (int j = 0; j < 9; ++j) acc[j] = 0.f;
  int k = start + part;
  for (; k + 8 < end; k += 16){
    unsigned w0 = sorted[k], w1 = sorted[k+8];
    int sA = w0 >> 6, sB = w1 >> 6;
    float eA = ex2[sA], eB = ex2[sB];
    float4 raA = *(const float4*)(rep + (size_t)sA*D_H);
    float4 rbA = *(const float4*)(rep + (size_t)sA*D_H + 4);
    float4 raB = *(const float4*)(rep + (size_t)sB*D_H);
    float4 rbB = *(const float4*)(rep + (size_t)sB*D_H + 4);
    acc[0] += eA*raA.x; acc[1] += eA*raA.y; acc[2] += eA*raA.z; acc[3] += eA*raA.w;
    acc[4] += eA*rbA.x; acc[5] += eA*rbA.y; acc[6] += eA*rbA.z; acc[7] += eA*rbA.w;
    acc[8] += eA;
    acc[0] += eB*raB.x; acc[1] += eB*raB.y; acc[2] += eB*raB.z; acc[3] += eB*raB.w;
    acc[4] += eB*rbB.x; acc[5] += eB*rbB.y; acc[6] += eB*rbB.z; acc[7] += eB*rbB.w;
    acc[8] += eB;
  }
  if (k < end){
    unsigned w = sorted[k];
    int s = w >> 6;
    float E = ex2[s];
    float4 ra = *(const float4*)(rep + (size_t)s*D_H);
    float4 rb = *(const float4*)(rep + (size_t)s*D_H + 4);
    acc[0] += E*ra.x; acc[1] += E*ra.y; acc[2] += E*ra.z; acc[3] += E*ra.w;
    acc[4] += E*rb.x; acc[5] += E*rb.y; acc[6] += E*rb.z; acc[7] += E*rb.w;
    acc[8] += E;
  }
  // combine across the 8 lanes of the slot group
#pragma unroll
  for (int j = 0; j < 9; ++j){
    acc[j] += __shfl_xor(acc[j], 1, 64);
    acc[j] += __shfl_xor(acc[j], 2, 64);
    acc[j] += __shfl_xor(acc[j], 4, 64);
  }
  if (part == 0){
    acc[8] += 1.0f;   // analytic self-loop: rep[masked]=0 -> ex2=1, denom-only
#pragma unroll
    for (int j = 0; j < 9; ++j) comb[c*9 + j] = acc[j];
  }
  __syncthreads();
  // fused loss: 8 waves sweep the tile's slots (wave-uniform comb reads -> broadcast)
  int wv = tid >> 6, lane = tid & 63;
  float accv = 0.f;
  for (int sl = wv; sl < TSD; sl += 8){
    int slot = sg*TSD + sl;
    if (slot >= N_MASK) break;
    const float* a = comb + sl*9;
    float inv = 1.0f / a[8];
    int node = mask_nodes[slot];
    float dot = 0.f, na = 0.f, nb = 0.f;
#pragma unroll
    for (int hh = 0; hh < 2; ++hh){
      int f = lane + 64*hh;
      float r = dec_b[f];
#pragma unroll
      for (int kk = 0; kk < D_H; ++kk) r += a[kk]*inv*Wt[kk*D_IN + f];
      r = lrelu(r, 0.01f);
      float xi = x[(size_t)node*D_IN + f];
      dot += r*xi; na += r*r; nb += xi*xi;
    }
    dot = wave_sum(dot); na = wave_sum(na); nb = wave_sum(nb);
    if (lane == 0) accv += dot / (fmaxf(sqrtf(na), 1e-8f)*fmaxf(sqrtf(nb), 1e-8f));
  }
  if (lane == 0) wsum[wv] = accv;
  __syncthreads();
  if (tid == 0){
    float b = 0.f;
#pragma unroll
    for (int q = 0; q < 8; ++q) b += wsum[q];
    atomicAdd(cos_sum, b);
    __threadfence();
    int t = atomicAdd(ticket, 1);
    if (t == gridDim.x - 1){
      float cc = atomicAdd(cos_sum, 0.0f);   // atomic read-after-all
      out[0] = 1.0f - cc / (float)N_MASK;
    }
  }
}

extern "C" void kernel_launch(void* const* d_in, const int* in_sizes, int n_in,
                              void* d_out, int out_size, void* d_ws, size_t ws_size,
                              hipStream_t stream){
  const float* x          = (const float*)d_in[0];
  const int*   ei         = (const int*)  d_in[1];
  const int*   mask_nodes = (const int*)  d_in[2];
  const float* token      = (const float*)d_in[3];
  const float* enc_W      = (const float*)d_in[4];
  const float* enc_as     = (const float*)d_in[5];
  const float* enc_ad     = (const float*)d_in[6];
  const float* enc_b      = (const float*)d_in[7];
  const float* e2d_W      = (const float*)d_in[8];
  const float* dec_W      = (const float*)d_in[9];
  const float* dec_as     = (const float*)d_in[10];
  const float* dec_b      = (const float*)d_in[12];
  float* out = (float*)d_out;

  char* w = (char*)d_ws;
  size_t off = 0;
  auto alloc = [&](size_t bytes)->char*{ char* p = w + off; off += (bytes + 255)/256*256; return p; };
  int*   gcur_enc = (int*)  alloc(NTE*4);
  int*   gcur_dec = (int*)  alloc(NTD*4);
  float* cos_sum  = (float*)alloc(4);
  int*   ticket   = (int*)  alloc(4);
  int*      mask_slot = (int*)     alloc((size_t)N_NODES*4);
  unsigned* be        = (unsigned*)alloc((size_t)NTE*CAPB*4);
  unsigned* bd        = (unsigned*)alloc((size_t)NTD*CAPD*4);
  float*    h1        = (float*)   alloc((size_t)N_NODES*D_H*4);
  float*    as1       = (float*)   alloc((size_t)N_NODES*4);
  float*    ad1       = (float*)   alloc((size_t)N_NODES*4);
  float*    rep       = (float*)   alloc((size_t)N_NODES*D_H*4);
  float*    ex2       = (float*)   alloc((size_t)N_NODES*4);
  float*    vvec      = (float*)   alloc(64);

  k_init    <<<(N_NODES + 511)/512, 512, 0, stream>>>(mask_slot, gcur_enc, gcur_dec, cos_sum, ticket);
  k_ms      <<<(N_MASK + 255)/256, 256, 0, stream>>>(mask_nodes, mask_slot, dec_W, dec_as, vvec);
  k_pre     <<<NB_NODE + NB_BKT, 512, 0, stream>>>(x, token, enc_W, enc_as, enc_ad, mask_slot,
                                                   ei, h1, as1, ad1, gcur_enc, gcur_dec, be, bd);
  k_agg_enc <<<NTE, 512, 0, stream>>>(be, gcur_enc, as1, ad1, h1, enc_b, e2d_W, mask_slot,
                                      vvec, out + 1, rep, ex2);
  k_agg_dec <<<NTD, 512, 0, stream>>>(bd, gcur_dec, ex2, rep, dec_W, dec_b, mask_nodes, x,
                                      cos_sum, ticket, out);
}

// Round 21
// 87.032 us; speedup vs baseline: 1.6145x; 1.0629x over previous
//
#include <hip/hip_runtime.h>

#define N_NODES 100000
#define N_EDGES 1600000
#define D_IN    128
#define D_H     8
#define N_MASK  10000

#define TS      256       // enc tile size (nodes per tile); loc fits in 8 bits
#define NTE     391       // ceil(N_NODES/TS)
#define CAPB    5760      // enc bucket capacity
#define TSD     64        // dec tile size (slots per tile); loc fits in 6 bits
#define NTD     157       // ceil(N_MASK/TSD)
#define CAPD    1536      // dec bucket capacity
#define NB_NODE 196       // node blocks in k_pre (512 nodes/block, thread-per-node)
#define EPB     2048      // edges per bucket block
#define NB_BKT  782       // ceil(N_EDGES/EPB)

__device__ __forceinline__ float lrelu(float v, float s){ return v > 0.f ? v : s*v; }

__device__ __forceinline__ float wave_sum(float v){
#pragma unroll
  for (int o = 32; o > 0; o >>= 1) v += __shfl_xor(v, o, 64);
  return v;
}

// merged init+scatter: each block owns a 512-node range (write -1, then scan the
// 10k mask list for entries in-range -> no cross-block race). Block 0: cursors+vvec.
__global__ void __launch_bounds__(512) k_setup(const int* __restrict__ mask_nodes,
                        int* __restrict__ mask_slot,
                        int* __restrict__ gcur_enc, int* __restrict__ gcur_dec,
                        float* __restrict__ cos_sum, int* __restrict__ ticket,
                        const float* __restrict__ Wd, const float* __restrict__ a_src,
                        float* __restrict__ vvec){
  int tid = threadIdx.x;
  int base = blockIdx.x*512;
  int i = base + tid;
  if (i < N_NODES) mask_slot[i] = -1;
  if (blockIdx.x == 0){
    if (tid < NTE) gcur_enc[tid] = 0;
    if (tid < NTD) gcur_dec[tid] = 0;
    if (tid == 0){ cos_sum[0] = 0.f; ticket[0] = 0; }
    if (tid < D_H){
      float s = 0.f;
      for (int j = 0; j < D_IN; ++j) s += a_src[j] * Wd[j*D_H + tid];
      vvec[tid] = s;
    }
  }
  __syncthreads();   // -1 writes for this block's range complete
  int hi = min(base + 512, N_NODES);
  for (int k = tid; k < N_MASK; k += 512){
    int node = mask_nodes[k];
    if (node >= base && node < hi) mask_slot[node] = k;
  }
}

// fused: blocks [0,NB_NODE)              = encoder node stage, thread-per-node (broadcast Ws)
//        blocks [NB_NODE,NB_NODE+NB_BKT) = edge bucketing (2048/block, reg-cached 2-pass)
__global__ void __launch_bounds__(512) k_pre(
    const float* __restrict__ x, const float* __restrict__ token,
    const float* __restrict__ W, const float* __restrict__ a_src,
    const float* __restrict__ a_dst, const int* __restrict__ mask_slot,
    const int* __restrict__ ei,
    float* __restrict__ h1, float* __restrict__ as1, float* __restrict__ ad1,
    int* __restrict__ gcur_enc, int* __restrict__ gcur_dec,
    unsigned* __restrict__ be, unsigned* __restrict__ bd){
  __shared__ int smem[1104];   // node: Ws(1024)+sa+sd ; bucket: hist/base arrays
  if (blockIdx.x < NB_NODE){
    float* Ws = (float*)smem;
    float* sa = Ws + D_H*D_IN;
    float* sd = sa + D_H;
    for (int t = threadIdx.x; t < D_H*D_IN; t += 512) Ws[t] = W[t];
    if (threadIdx.x < D_H)            sa[threadIdx.x] = a_src[threadIdx.x];
    else if (threadIdx.x < 2*D_H)     sd[threadIdx.x - D_H] = a_dst[threadIdx.x - D_H];
    __syncthreads();
    int wid = blockIdx.x*512 + threadIdx.x;
    if (wid >= N_NODES) return;
    const float* row = (mask_slot[wid] >= 0) ? token : (x + (size_t)wid*D_IN);
    float acc[D_H];
#pragma unroll
    for (int j = 0; j < D_H; ++j) acc[j] = 0.f;
#pragma unroll 8
    for (int i = 0; i < D_IN/4; ++i){
      float4 xc = *(const float4*)(row + 4*i);
#pragma unroll
      for (int j = 0; j < D_H; ++j){
        float4 wv = *(const float4*)(Ws + j*D_IN + 4*i);   // wave-uniform -> LDS broadcast
        acc[j] += xc.x*wv.x + xc.y*wv.y + xc.z*wv.z + xc.w*wv.w;
      }
    }
    float as = 0.f, ad = 0.f;
#pragma unroll
    for (int j = 0; j < D_H; ++j){ as += acc[j]*sa[j]; ad += acc[j]*sd[j]; }
    float4* hp = (float4*)(h1 + (size_t)wid*D_H);
    hp[0] = make_float4(acc[0], acc[1], acc[2], acc[3]);
    hp[1] = make_float4(acc[4], acc[5], acc[6], acc[7]);
    as1[wid] = as; ad1[wid] = ad;
  } else {
    int* h_enc    = smem;                  // [NTE]
    int* base_enc = h_enc + NTE;           // [NTE]
    int* h_dec    = base_enc + NTE;        // [NTD]
    int* base_dec = h_dec + NTD;           // [NTD]
    int tid = threadIdx.x;
    if (tid < NTE) h_enc[tid] = 0;
    if (tid < NTD) h_dec[tid] = 0;
    __syncthreads();
    int t0 = (blockIdx.x - NB_NODE)*EPB;
    int s[4], d[4], sl[4];
#pragma unroll
    for (int k = 0; k < 4; ++k){
      int t = t0 + tid + k*512;
      s[k] = -1;
      if (t < N_EDGES){
        s[k] = ei[t]; d[k] = ei[N_EDGES + t];
        sl[k] = mask_slot[d[k]];
        atomicAdd(&h_enc[d[k] >> 8], 1);
        if (sl[k] >= 0) atomicAdd(&h_dec[sl[k] >> 6], 1);
      }
    }
    __syncthreads();
    if (tid < NTE){ base_enc[tid] = atomicAdd(&gcur_enc[tid], h_enc[tid]); h_enc[tid] = 0; }
    if (tid < NTD){ base_dec[tid] = atomicAdd(&gcur_dec[tid], h_dec[tid]); h_dec[tid] = 0; }
    __syncthreads();
#pragma unroll
    for (int k = 0; k < 4; ++k){
      if (s[k] >= 0){
        int b = d[k] >> 8, loc = d[k] & 255;
        int idx = base_enc[b] + atomicAdd(&h_enc[b], 1);
        if (idx < CAPB) be[(size_t)b*CAPB + idx] = ((unsigned)s[k] << 8) | (unsigned)loc;
        if (sl[k] >= 0){
          int bs = sl[k] >> 6, locs = sl[k] & 63;
          int i2 = base_dec[bs] + atomicAdd(&h_dec[bs], 1);
          if (i2 < CAPD) bd[(size_t)bs*CAPD + i2] = ((unsigned)s[k] << 6) | (unsigned)locs;
        }
      }
    }
  }
}

// one block per enc tile: counting-sort bucket by loc in LDS, then 2 threads/node
// register accumulation (unroll-4), combine, analytic self-loop, fused enc_fin epilogue.
__global__ void __launch_bounds__(512) k_agg_enc(const unsigned* __restrict__ be,
                          const int* __restrict__ gcur_enc,
                          const float* __restrict__ as1, const float* __restrict__ ad1,
                          const float* __restrict__ h1,
                          const float* __restrict__ enc_b, const float* __restrict__ e2dW,
                          const int* __restrict__ mask_slot, const float* __restrict__ v,
                          float* __restrict__ out_rep, float* __restrict__ rep,
                          float* __restrict__ ex2){
  __shared__ unsigned sorted[CAPB];
  __shared__ int hist[TS], off[TS], cur[TS];
  __shared__ float lad[TS];
  __shared__ float comb[TS*9];
  int tau = blockIdx.x, tid = threadIdx.x;
  int gb = tau*TS;
  if (tid < TS){
    hist[tid] = 0;
    int g = gb + tid; lad[tid] = (g < N_NODES) ? ad1[g] : 0.f;
  }
  __syncthreads();
  int n = min(gcur_enc[tau], CAPB);
  const unsigned* bb = be + (size_t)tau*CAPB;
  for (int i = tid; i < n; i += 512) atomicAdd(&hist[bb[i] & 255], 1);
  __syncthreads();
  if (tid < TS) off[tid] = hist[tid];
  __syncthreads();
#pragma unroll
  for (int s2 = 1; s2 < TS; s2 <<= 1){          // inclusive prefix sum (Hillis-Steele)
    int vv = 0;
    if (tid < TS && tid >= s2) vv = off[tid - s2];
    __syncthreads();
    if (tid < TS) off[tid] += vv;
    __syncthreads();
  }
  if (tid < TS) cur[tid] = off[tid] - hist[tid];   // exclusive start
  __syncthreads();
  for (int i = tid; i < n; i += 512){
    unsigned w = bb[i];
    int pos = atomicAdd(&cur[w & 255], 1);
    sorted[pos] = w;
  }
  __syncthreads();
  // phase 2: 2 threads per node, register accumulation over sorted run halves
  int c = tid & 255, half = tid >> 8;
  int start = off[c] - hist[c], deg = hist[c];
  int mid = start + ((deg + 1) >> 1), end = start + deg;
  int k0 = half ? mid : start, k1 = half ? end : mid;
  float adv = lad[c];
  float acc[9];
#pragma unroll
  for (int j = 0; j < 9; ++j) acc[j] = 0.f;
  auto edge1 = [&](unsigned w){
    int s = w >> 8;
    float as = as1[s];
    float4 ha = *(const float4*)(h1 + (size_t)s*D_H);
    float4 hb = *(const float4*)(h1 + (size_t)s*D_H + 4);
    float ex = __expf(lrelu(as + adv, 0.2f));
    acc[0] += ex*ha.x; acc[1] += ex*ha.y; acc[2] += ex*ha.z; acc[3] += ex*ha.w;
    acc[4] += ex*hb.x; acc[5] += ex*hb.y; acc[6] += ex*hb.z; acc[7] += ex*hb.w;
    acc[8] += ex;
  };
  int k = k0;
  for (; k + 4 <= k1; k += 4){
    unsigned w0 = sorted[k], w1 = sorted[k+1], w2 = sorted[k+2], w3 = sorted[k+3];
    int s0 = w0 >> 8, s1 = w1 >> 8, s2 = w2 >> 8, s3 = w3 >> 8;
    float a0 = as1[s0], a1 = as1[s1], a2 = as1[s2], a3 = as1[s3];
    float4 h0a = *(const float4*)(h1 + (size_t)s0*D_H), h0b = *(const float4*)(h1 + (size_t)s0*D_H + 4);
    float4 h1a = *(const float4*)(h1 + (size_t)s1*D_H), h1b = *(const float4*)(h1 + (size_t)s1*D_H + 4);
    float4 h2a = *(const float4*)(h1 + (size_t)s2*D_H), h2b = *(const float4*)(h1 + (size_t)s2*D_H + 4);
    float4 h3a = *(const float4*)(h1 + (size_t)s3*D_H), h3b = *(const float4*)(h1 + (size_t)s3*D_H + 4);
    float e0 = __expf(lrelu(a0 + adv, 0.2f));
    float e1 = __expf(lrelu(a1 + adv, 0.2f));
    float e2 = __expf(lrelu(a2 + adv, 0.2f));
    float e3 = __expf(lrelu(a3 + adv, 0.2f));
    acc[0] += e0*h0a.x + e1*h1a.x + e2*h2a.x + e3*h3a.x;
    acc[1] += e0*h0a.y + e1*h1a.y + e2*h2a.y + e3*h3a.y;
    acc[2] += e0*h0a.z + e1*h1a.z + e2*h2a.z + e3*h3a.z;
    acc[3] += e0*h0a.w + e1*h1a.w + e2*h2a.w + e3*h3a.w;
    acc[4] += e0*h0b.x + e1*h1b.x + e2*h2b.x + e3*h3b.x;
    acc[5] += e0*h0b.y + e1*h1b.y + e2*h2b.y + e3*h3b.y;
    acc[6] += e0*h0b.z + e1*h1b.z + e2*h2b.z + e3*h3b.z;
    acc[7] += e0*h0b.w + e1*h1b.w + e2*h2b.w + e3*h3b.w;
    acc[8] += e0 + e1 + e2 + e3;
  }
  for (; k < k1; ++k) edge1(sorted[k]);
  if (half){
#pragma unroll
    for (int j = 0; j < 9; ++j) comb[c*9 + j] = acc[j];
  }
  __syncthreads();
  if (!half){
    int i = gb + c;
    if (i < N_NODES){
#pragma unroll
      for (int j = 0; j < 9; ++j) acc[j] += comb[c*9 + j];
      // analytic self-loop
      {
        float exs = __expf(lrelu(as1[i] + adv, 0.2f));
        float4 ha = *(const float4*)(h1 + (size_t)i*D_H);
        float4 hb = *(const float4*)(h1 + (size_t)i*D_H + 4);
        acc[0] += exs*ha.x; acc[1] += exs*ha.y; acc[2] += exs*ha.z; acc[3] += exs*ha.w;
        acc[4] += exs*hb.x; acc[5] += exs*hb.y; acc[6] += exs*hb.z; acc[7] += exs*hb.w;
        acc[8] += exs;
      }
      float inv = 1.0f / acc[8];
      float er[D_H];
#pragma unroll
      for (int j = 0; j < D_H; ++j){
        er[j] = lrelu(acc[j]*inv + enc_b[j], 0.01f);
        out_rep[(size_t)i*D_H + j] = er[j];
      }
      bool masked = mask_slot[i] >= 0;
      float as = 0.f;
      float rv[D_H];
#pragma unroll
      for (int kk = 0; kk < D_H; ++kk){
        float t = 0.f;
#pragma unroll
        for (int j = 0; j < D_H; ++j) t += er[j]*e2dW[kk*D_H + j];
        t = masked ? 0.f : t;
        rv[kk] = t;
        as += t * v[kk];
      }
      float4* rp = (float4*)(rep + (size_t)i*D_H);
      rp[0] = make_float4(rv[0], rv[1], rv[2], rv[3]);
      rp[1] = make_float4(rv[4], rv[5], rv[6], rv[7]);
      ex2[i] = __expf(lrelu(as, 0.2f));  // alpha_dst[masked]=0 -> weight depends only on src
    }
  }
}

// one block per dec tile (157): sort 64-bin, 8 threads/slot register-accumulate,
// shfl-combine, analytic self-loop (+1 denom), fused cosine loss.
__global__ void __launch_bounds__(512) k_agg_dec(const unsigned* __restrict__ bd,
                          const int* __restrict__ gcur_dec,
                          const float* __restrict__ ex2, const float* __restrict__ rep,
                          const float* __restrict__ Wd, const float* __restrict__ dec_b,
                          const int* __restrict__ mask_nodes, const float* __restrict__ x,
                          float* __restrict__ cos_sum, int* __restrict__ ticket,
                          float* __restrict__ out){
  __shared__ unsigned sorted[CAPD];
  __shared__ int hist[TSD], off[TSD], cur[TSD];
  __shared__ float comb[TSD*9];
  __shared__ float Wt[D_H*D_IN];    // transposed: Wt[k*128+f] = Wd[f*8+k]
  __shared__ float wsum[8];
  int sg = blockIdx.x, tid = threadIdx.x;
  if (tid < TSD) hist[tid] = 0;
  for (int t = tid; t < D_H*D_IN; t += 512) Wt[(t & 7)*D_IN + (t >> 3)] = Wd[t];
  __syncthreads();
  int n = min(gcur_dec[sg], CAPD);
  const unsigned* bb = bd + (size_t)sg*CAPD;
  for (int i = tid; i < n; i += 512) atomicAdd(&hist[bb[i] & 63], 1);
  __syncthreads();
  if (tid < TSD) off[tid] = hist[tid];
  __syncthreads();
#pragma unroll
  for (int s2 = 1; s2 < TSD; s2 <<= 1){
    int vv = 0;
    if (tid < TSD && tid >= s2) vv = off[tid - s2];
    __syncthreads();
    if (tid < TSD) off[tid] += vv;
    __syncthreads();
  }
  if (tid < TSD) cur[tid] = off[tid] - hist[tid];
  __syncthreads();
  for (int i = tid; i < n; i += 512){
    unsigned w = bb[i];
    int pos = atomicAdd(&cur[w & 63], 1);
    sorted[pos] = w;
  }
  __syncthreads();
  // 8 threads per slot: strided walk, unroll-2
  int c = tid >> 3, part = tid & 7;
  int start = off[c] - hist[c], deg = hist[c], end = start + deg;
  float acc[9];
#pragma unroll
  for (int j = 0; j < 9; ++j) acc[j] = 0.f;
  int k = start + part;
  for (; k + 8 < end; k += 16){
    unsigned w0 = sorted[k], w1 = sorted[k+8];
    int sA = w0 >> 6, sB = w1 >> 6;
    float eA = ex2[sA], eB = ex2[sB];
    float4 raA = *(const float4*)(rep + (size_t)sA*D_H);
    float4 rbA = *(const float4*)(rep + (size_t)sA*D_H + 4);
    float4 raB = *(const float4*)(rep + (size_t)sB*D_H);
    float4 rbB = *(const float4*)(rep + (size_t)sB*D_H + 4);
    acc[0] += eA*raA.x; acc[1] += eA*raA.y; acc[2] += eA*raA.z; acc[3] += eA*raA.w;
    acc[4] += eA*rbA.x; acc[5] += eA*rbA.y; acc[6] += eA*rbA.z; acc[7] += eA*rbA.w;
    acc[8] += eA;
    acc[0] += eB*raB.x; acc[1] += eB*raB.y; acc[2] += eB*raB.z; acc[3] += eB*raB.w;
    acc[4] += eB*rbB.x; acc[5] += eB*rbB.y; acc[6] += eB*rbB.z; acc[7] += eB*rbB.w;
    acc[8] += eB;
  }
  if (k < end){
    unsigned w = sorted[k];
    int s = w >> 6;
    float E = ex2[s];
    float4 ra = *(const float4*)(rep + (size_t)s*D_H);
    float4 rb = *(const float4*)(rep + (size_t)s*D_H + 4);
    acc[0] += E*ra.x; acc[1] += E*ra.y; acc[2] += E*ra.z; acc[3] += E*ra.w;
    acc[4] += E*rb.x; acc[5] += E*rb.y; acc[6] += E*rb.z; acc[7] += E*rb.w;
    acc[8] += E;
  }
  // combine across the 8 lanes of the slot group
#pragma unroll
  for (int j = 0; j < 9; ++j){
    acc[j] += __shfl_xor(acc[j], 1, 64);
    acc[j] += __shfl_xor(acc[j], 2, 64);
    acc[j] += __shfl_xor(acc[j], 4, 64);
  }
  if (part == 0){
    acc[8] += 1.0f;   // analytic self-loop: rep[masked]=0 -> ex2=1, denom-only
#pragma unroll
    for (int j = 0; j < 9; ++j) comb[c*9 + j] = acc[j];
  }
  __syncthreads();
  // fused loss: 8 waves sweep the tile's slots (wave-uniform comb reads -> broadcast)
  int wv = tid >> 6, lane = tid & 63;
  float accv = 0.f;
  for (int sl = wv; sl < TSD; sl += 8){
    int slot = sg*TSD + sl;
    if (slot >= N_MASK) break;
    const float* a = comb + sl*9;
    float inv = 1.0f / a[8];
    int node = mask_nodes[slot];
    float dot = 0.f, na = 0.f, nb = 0.f;
#pragma unroll
    for (int hh = 0; hh < 2; ++hh){
      int f = lane + 64*hh;
      float r = dec_b[f];
#pragma unroll
      for (int kk = 0; kk < D_H; ++kk) r += a[kk]*inv*Wt[kk*D_IN + f];
      r = lrelu(r, 0.01f);
      float xi = x[(size_t)node*D_IN + f];
      dot += r*xi; na += r*r; nb += xi*xi;
    }
    dot = wave_sum(dot); na = wave_sum(na); nb = wave_sum(nb);
    if (lane == 0) accv += dot / (fmaxf(sqrtf(na), 1e-8f)*fmaxf(sqrtf(nb), 1e-8f));
  }
  if (lane == 0) wsum[wv] = accv;
  __syncthreads();
  if (tid == 0){
    float b = 0.f;
#pragma unroll
    for (int q = 0; q < 8; ++q) b += wsum[q];
    atomicAdd(cos_sum, b);
    __threadfence();
    int t = atomicAdd(ticket, 1);
    if (t == gridDim.x - 1){
      float cc = atomicAdd(cos_sum, 0.0f);   // atomic read-after-all
      out[0] = 1.0f - cc / (float)N_MASK;
    }
  }
}

extern "C" void kernel_launch(void* const* d_in, const int* in_sizes, int n_in,
                              void* d_out, int out_size, void* d_ws, size_t ws_size,
                              hipStream_t stream){
  const float* x          = (const float*)d_in[0];
  const int*   ei         = (const int*)  d_in[1];
  const int*   mask_nodes = (const int*)  d_in[2];
  const float* token      = (const float*)d_in[3];
  const float* enc_W      = (const float*)d_in[4];
  const float* enc_as     = (const float*)d_in[5];
  const float* enc_ad     = (const float*)d_in[6];
  const float* enc_b      = (const float*)d_in[7];
  const float* e2d_W      = (const float*)d_in[8];
  const float* dec_W      = (const float*)d_in[9];
  const float* dec_as     = (const float*)d_in[10];
  const float* dec_b      = (const float*)d_in[12];
  float* out = (float*)d_out;

  char* w = (char*)d_ws;
  size_t off = 0;
  auto alloc = [&](size_t bytes)->char*{ char* p = w + off; off += (bytes + 255)/256*256; return p; };
  int*   gcur_enc = (int*)  alloc(NTE*4);
  int*   gcur_dec = (int*)  alloc(NTD*4);
  float* cos_sum  = (float*)alloc(4);
  int*   ticket   = (int*)  alloc(4);
  int*      mask_slot = (int*)     alloc((size_t)N_NODES*4);
  unsigned* be        = (unsigned*)alloc((size_t)NTE*CAPB*4);
  unsigned* bd        = (unsigned*)alloc((size_t)NTD*CAPD*4);
  float*    h1        = (float*)   alloc((size_t)N_NODES*D_H*4);
  float*    as1       = (float*)   alloc((size_t)N_NODES*4);
  float*    ad1       = (float*)   alloc((size_t)N_NODES*4);
  float*    rep       = (float*)   alloc((size_t)N_NODES*D_H*4);
  float*    ex2       = (float*)   alloc((size_t)N_NODES*4);
  float*    vvec      = (float*)   alloc(64);

  k_setup   <<<NB_NODE, 512, 0, stream>>>(mask_nodes, mask_slot, gcur_enc, gcur_dec,
                                          cos_sum, ticket, dec_W, dec_as, vvec);
  k_pre     <<<NB_NODE + NB_BKT, 512, 0, stream>>>(x, token, enc_W, enc_as, enc_ad, mask_slot,
                                                   ei, h1, as1, ad1, gcur_enc, gcur_dec, be, bd);
  k_agg_enc <<<NTE, 512, 0, stream>>>(be, gcur_enc, as1, ad1, h1, enc_b, e2d_W, mask_slot,
                                      vvec, out + 1, rep, ex2);
  k_agg_dec <<<NTD, 512, 0, stream>>>(bd, gcur_dec, ex2, rep, dec_W, dec_b, mask_nodes, x,
                                      cos_sum, ticket, out);
}